// Round 11
// baseline (368.412 us; speedup 1.0000x reference)
//
#include <hip/hip_runtime.h>
#include <math.h>

#define Bdim 8
#define Sdim 1024
#define Hdim 1024
#define NHd 16
#define HDd 64
#define N3H 3072

// ws layout (ushort elements)
// Q: [bh][s][128] row-major (hi|lo). K: [bh][16 tiles][8192] fragment-ordered.
// V: [bh][16 tiles][4096] fragment-ordered. W^T hi/lo planes after.
#define Q_OFF   0u
#define K_OFF   16777216u
#define V_OFF   33554432u
#define WH_OFF  41943040u
#define WL_OFF  45088768u
// d_out scratch layout (ushort elements): Ahi, Alo
#define AHI_OFF 0u
#define ALO_OFF 8388608u

typedef __bf16 bf16x8 __attribute__((ext_vector_type(8)));
typedef float  f32x4  __attribute__((ext_vector_type(4)));

__device__ __forceinline__ unsigned short f2bf(float x) {
  unsigned b = __builtin_bit_cast(unsigned, x);
  return (unsigned short)((b + 0x7FFFu + ((b >> 16) & 1u)) >> 16);
}
__device__ __forceinline__ float bf2f(unsigned short h) {
  unsigned b = ((unsigned)h) << 16;
  return __builtin_bit_cast(float, b);
}
__device__ __forceinline__ void split_hl(float v, unsigned short& h, unsigned short& l) {
  h = f2bf(v);
  l = f2bf(v - bf2f(h));
}
__device__ __forceinline__ void async16(void* lds, const void* g) {
  __builtin_amdgcn_global_load_lds((const __attribute__((address_space(1))) unsigned int*)g,
                                   (__attribute__((address_space(3))) unsigned int*)lds, 16, 0, 0);
}

// DPP-based 16-lane max reduce: masks {1,2,7,15} span (Z/2)^4 and are all DPP row-ops
// (quad_perm 0xB1 = xor1, quad_perm 0x4E = xor2, row_half_mirror 0x141 = xor7,
//  row_mirror 0x140 = xor15). VALU-pipe only — no ds_swizzle traffic.
template <int CTRL>
__device__ __forceinline__ float dppmax(float v) {
  int x = __builtin_amdgcn_mov_dpp(__builtin_bit_cast(int, v), CTRL, 0xf, 0xf, true);
  return fmaxf(v, __builtin_bit_cast(float, x));
}
__device__ __forceinline__ float rowmax16(float v) {
  v = dppmax<0xB1>(v);
  v = dppmax<0x4E>(v);
  v = dppmax<0x141>(v);
  v = dppmax<0x140>(v);
  return v;
}

// native base-2 exponential (v_exp_f32)
__device__ __forceinline__ float exp2g(float x) { return __builtin_amdgcn_exp2f(x); }

// ---------- fused convert: A -> hi/lo planes (d_out scratch); W -> W^T hi/lo (ws) ----------
__global__ __launch_bounds__(256) void convert_AW(
    const float* __restrict__ A, const float* __restrict__ W,
    unsigned short* __restrict__ aout, unsigned short* __restrict__ ws)
{
  __shared__ float T[64][65];
  const int tid = threadIdx.x;
  int bid = blockIdx.x;
  if (bid < 4096) {
    size_t i = ((size_t)bid * 256 + tid) * 8;
    float4 a0 = *(const float4*)&A[i];
    float4 a1 = *(const float4*)&A[i + 4];
    float av[8] = {a0.x, a0.y, a0.z, a0.w, a1.x, a1.y, a1.z, a1.w};
    unsigned short h[8], l[8];
    #pragma unroll
    for (int j = 0; j < 8; ++j) split_hl(av[j], h[j], l[j]);
    *(uint4*)&aout[AHI_OFF + i] = *(uint4*)h;
    *(uint4*)&aout[ALO_OFF + i] = *(uint4*)l;
    return;
  }
  bid -= 4096;
  const int n0 = (bid % (N3H / 64)) * 64;
  const int k0 = (bid / (N3H / 64)) * 64;
  #pragma unroll
  for (int r = 0; r < 4; ++r) {
    int k = r * 16 + (tid >> 4);
    int n = (tid & 15) * 4;
    float4 v = *(const float4*)&W[(size_t)(k0 + k) * N3H + n0 + n];
    T[k][n + 0] = v.x; T[k][n + 1] = v.y; T[k][n + 2] = v.z; T[k][n + 3] = v.w;
  }
  __syncthreads();
  int n = tid >> 2;
  int kl = (tid & 3) * 16;
  unsigned short h[16], l[16];
  #pragma unroll
  for (int i = 0; i < 16; ++i) split_hl(T[kl + i][n], h[i], l[i]);
  size_t base = (size_t)(n0 + n) * 1024 + k0 + kl;
  *(uint4*)&ws[WH_OFF + base]     = *(uint4*)&h[0];
  *(uint4*)&ws[WH_OFF + base + 8] = *(uint4*)&h[8];
  *(uint4*)&ws[WL_OFF + base]     = *(uint4*)&l[0];
  *(uint4*)&ws[WL_OFF + base + 8] = *(uint4*)&l[8];
}

// ---------- MFMA QKV GEMM: C = A(8192x1024) * W(1024x3072) + bias ----------
// (R0 version: 128x128 tile, 16x16x32, 2 blocks/CU — proven 152-155 us. FROZEN.)
__global__ __launch_bounds__(256, 2) void qkv_mfma(
    const unsigned short* __restrict__ ao,
    const unsigned short* __restrict__ ws,
    const float* __restrict__ bias,
    unsigned short* __restrict__ wso)
{
  __shared__ unsigned short sA[2][128 * 32];
  __shared__ unsigned short sB[2][128 * 32];

  const int tid  = threadIdx.x;
  const int wave = tid >> 6;
  const int lane = tid & 63;
  const int l16  = lane & 15;
  const int quad = lane >> 4;

  const int n0 = blockIdx.x * 128;
  const int m0 = blockIdx.y * 128;
  const int wm = (wave >> 1) * 64;
  const int wn = (wave & 1) * 64;

  const unsigned short* Ah = ao + AHI_OFF;
  const unsigned short* Al = ao + ALO_OFF;
  const unsigned short* Wh = ws + WH_OFF;
  const unsigned short* Wl = ws + WL_OFF;

  f32x4 acc[4][4];
  #pragma unroll
  for (int i = 0; i < 4; ++i)
    #pragma unroll
    for (int j = 0; j < 4; ++j) acc[i][j] = (f32x4){0.f, 0.f, 0.f, 0.f};

  for (int kt = 0; kt < 1024; kt += 32) {
    __syncthreads();
    #pragma unroll
    for (int r = 0; r < 2; ++r) {
      int chunk = r * 256 + tid;
      int row = chunk >> 2;
      int c8  = (chunk & 3) << 3;
      int ldsoff = (r * 256 + wave * 64) * 8;
      async16(&sA[0][ldsoff], &Ah[(size_t)(m0 + row) * 1024 + kt + c8]);
      async16(&sA[1][ldsoff], &Al[(size_t)(m0 + row) * 1024 + kt + c8]);
      async16(&sB[0][ldsoff], &Wh[(size_t)(n0 + row) * 1024 + kt + c8]);
      async16(&sB[1][ldsoff], &Wl[(size_t)(n0 + row) * 1024 + kt + c8]);
    }
    __syncthreads();

    bf16x8 af[4][2], bf[4][2];
    #pragma unroll
    for (int i = 0; i < 4; ++i) {
      int row = wm + i * 16 + l16;
      af[i][0] = *(const bf16x8*)&sA[0][row * 32 + quad * 8];
      af[i][1] = *(const bf16x8*)&sA[1][row * 32 + quad * 8];
    }
    #pragma unroll
    for (int j = 0; j < 4; ++j) {
      int row = wn + j * 16 + l16;
      bf[j][0] = *(const bf16x8*)&sB[0][row * 32 + quad * 8];
      bf[j][1] = *(const bf16x8*)&sB[1][row * 32 + quad * 8];
    }
    #pragma unroll
    for (int i = 0; i < 4; ++i)
      #pragma unroll
      for (int j = 0; j < 4; ++j) {
        acc[i][j] = __builtin_amdgcn_mfma_f32_16x16x32_bf16(af[i][0], bf[j][0], acc[i][j], 0, 0, 0);
        acc[i][j] = __builtin_amdgcn_mfma_f32_16x16x32_bf16(af[i][1], bf[j][0], acc[i][j], 0, 0, 0);
        acc[i][j] = __builtin_amdgcn_mfma_f32_16x16x32_bf16(af[i][0], bf[j][1], acc[i][j], 0, 0, 0);
      }
  }

  const int ncol0 = n0 + wn;
  const int which = (ncol0 >> 6) % 3;
  const int head  = ncol0 / 192;
  const int mrow0 = m0 + wm;
  const int bb = mrow0 >> 10;
  const int sb = mrow0 & 1023;
  const int bh = bb * NHd + head;

  float bs[4];
  #pragma unroll
  for (int j = 0; j < 4; ++j) bs[j] = bias[ncol0 + j * 16 + l16];

  if (which == 0) {
    unsigned short* dst = wso + Q_OFF + ((size_t)bh * Sdim + sb) * 128;
    #pragma unroll
    for (int i = 0; i < 4; ++i)
      #pragma unroll
      for (int j = 0; j < 4; ++j) {
        int d = j * 16 + l16;
        #pragma unroll
        for (int r = 0; r < 4; ++r) {
          int s = i * 16 + quad * 4 + r;
          unsigned short h, l;
          split_hl(acc[i][j][r] + bs[j], h, l);
          dst[(size_t)s * 128 + d]      = h;
          dst[(size_t)s * 128 + 64 + d] = l;
        }
      }
  } else if (which == 1) {
    unsigned short* dst = wso + K_OFF + (size_t)bh * 131072 + (size_t)(sb >> 6) * 8192;
    #pragma unroll
    for (int i = 0; i < 4; ++i)
      #pragma unroll
      for (int j = 0; j < 4; ++j) {
        int c = j * 16 + l16;
        #pragma unroll
        for (int r = 0; r < 4; ++r) {
          int sp = i * 16 + quad * 4 + r;
          int idx = ((((sp >> 4) * 4 + (c >> 5)) * 64 + ((c >> 3) & 3) * 16 + (sp & 15)) << 3) + (c & 7);
          unsigned short h, l;
          split_hl(acc[i][j][r] + bs[j], h, l);
          dst[idx]        = h;
          dst[idx + 1024] = l;
        }
      }
  } else {
    unsigned short* dst = wso + V_OFF + (size_t)bh * 65536 + (size_t)(sb >> 6) * 4096;
    #pragma unroll
    for (int i = 0; i < 4; ++i)
      #pragma unroll
      for (int j = 0; j < 4; ++j) {
        int dr = j * 16 + l16;
        int ky = i * 16 + quad * 4;
        int idx = ((((dr >> 4) * 2 + (ky >> 5)) * 64 + ((ky >> 3) & 3) * 16 + (dr & 15)) << 3) + (ky & 7);
        unsigned short p[4];
        #pragma unroll
        for (int r = 0; r < 4; ++r) p[r] = f2bf(acc[i][j][r] + bs[j]);
        *(uint2*)&dst[idx] = *(uint2*)p;
      }
  }
}

// -------- MFMA flash attention: 128 q/block (32 q/wave), T14 reg-staged pipeline ---------
// R10 compute body unchanged. Staging: K/V tile t+1 lives in SIX NAMED uint4 registers
// (no array -> nothing for the allocator to demote, R4's rule-#20 failure mode).
// Issue is UNCONDITIONAL with clamped index. Barriers are raw {lgkmcnt(0); sched_barrier;
// s_barrier} — NO vmcnt(0) in the loop; the ds_write waits its own loads via counted
// register dependency, issued one full tile (~1200 cy) earlier. Drain leaves the
// per-tile critical path.
__global__ __launch_bounds__(256, 3) void attn_mfma(
    const unsigned short* __restrict__ qhl,
    const unsigned short* __restrict__ khl,   // fragment-ordered tiles
    const unsigned short* __restrict__ vt,    // fragment-ordered tiles
    const int* __restrict__ mask,
    float* __restrict__ out)
{
  __shared__ unsigned short Ks[8192];
  __shared__ unsigned short Vs[4096];
  __shared__ unsigned short Pw[4][2048];
  __shared__ unsigned short msks[1024];

  const int tid  = threadIdx.x;
  const int wave = tid >> 6;
  const int lane = tid & 63;
  const int l16  = lane & 15;
  const int quad = lane >> 4;

  const int xcd = blockIdx.x & 7;
  const int s_  = blockIdx.x >> 3;                           // 0..127
  const int bh  = xcd + ((s_ & 7) << 3) + ((s_ >> 6) << 6);  // 0..127 (bijective)
  const int qt  = (s_ >> 3) & 7;                             // 0..7
  const int bb  = bh >> 4;
  const int q0  = qt * 128;

  const float SCL = 11.5415603f;    // 8 * log2(e): softmax in exp2 domain (exact transform)
  const float MSKV = -14427.0f;     // -10000 * log2(e), rounded down

  const unsigned short* kplane = khl + (size_t)bh * 131072;
  const unsigned short* vplane = vt  + (size_t)bh * 65536;

#define BARRIER() do { \
    asm volatile("s_waitcnt lgkmcnt(0)" ::: "memory"); \
    __builtin_amdgcn_sched_barrier(0); \
    __builtin_amdgcn_s_barrier(); \
    __builtin_amdgcn_sched_barrier(0); \
  } while (0)

  // K/V staging registers: six NAMED uint4 (24 VGPR), never an array.
  uint4 kv0, kv1, kv2, kv3, kv4, kv5;

#define KV_ISSUE(t_) do { \
    int _t = (t_) < 15 ? (t_) : 15; \
    const unsigned short* _ks = kplane + (size_t)_t * 8192; \
    const unsigned short* _vs = vplane + (size_t)_t * 4096; \
    kv0 = *(const uint4*)&_ks[(size_t)(0 * 256 + tid) * 8]; \
    kv1 = *(const uint4*)&_ks[(size_t)(1 * 256 + tid) * 8]; \
    kv2 = *(const uint4*)&_ks[(size_t)(2 * 256 + tid) * 8]; \
    kv3 = *(const uint4*)&_ks[(size_t)(3 * 256 + tid) * 8]; \
    kv4 = *(const uint4*)&_vs[(size_t)(0 * 256 + tid) * 8]; \
    kv5 = *(const uint4*)&_vs[(size_t)(1 * 256 + tid) * 8]; \
  } while (0)

#define KV_WRITE() do { \
    *(uint4*)&Ks[(0 * 256 + tid) * 8] = kv0; \
    *(uint4*)&Ks[(1 * 256 + tid) * 8] = kv1; \
    *(uint4*)&Ks[(2 * 256 + tid) * 8] = kv2; \
    *(uint4*)&Ks[(3 * 256 + tid) * 8] = kv3; \
    *(uint4*)&Vs[(0 * 256 + tid) * 8] = kv4; \
    *(uint4*)&Vs[(1 * 256 + tid) * 8] = kv5; \
  } while (0)

  // all-ones B fragment for row-sum MFMA
  bf16x8 onesv;
  #pragma unroll
  for (int i = 0; i < 8; ++i) onesv[i] = (__bf16)1.0f;

  // ---- prologue: issue tile 0; mask + Q loads overlap its latency ----
  KV_ISSUE(0);

  {
    int4 mv = *(const int4*)&mask[bb * Sdim + tid * 4];
    msks[tid * 4 + 0] = (unsigned short)(mv.x ? 1 : 0);
    msks[tid * 4 + 1] = (unsigned short)(mv.y ? 1 : 0);
    msks[tid * 4 + 2] = (unsigned short)(mv.z ? 1 : 0);
    msks[tid * 4 + 3] = (unsigned short)(mv.w ? 1 : 0);
  }

  // Q fragments direct from global: group A rows = q0+wave*32+l16, group B = +16
  bf16x8 qfA[4], qfB[4];
  {
    int rowA = q0 + wave * 32 + l16;
    const unsigned short* srcA = qhl + ((size_t)bh * Sdim + rowA) * 128;
    const unsigned short* srcB = srcA + 16 * 128;
    #pragma unroll
    for (int kk = 0; kk < 4; ++kk) {
      qfA[kk] = *(const bf16x8*)&srcA[kk * 32 + quad * 8];
      qfB[kk] = *(const bf16x8*)&srcB[kk * 32 + quad * 8];
    }
  }

  KV_WRITE();        // counted vmcnt wait on kv via reg dep
  KV_ISSUE(1);
  BARRIER();         // Ks/Vs(0) + msks visible

  f32x4 OA[4] = {{0.f,0.f,0.f,0.f},{0.f,0.f,0.f,0.f},{0.f,0.f,0.f,0.f},{0.f,0.f,0.f,0.f}};
  f32x4 OB[4] = {{0.f,0.f,0.f,0.f},{0.f,0.f,0.f,0.f},{0.f,0.f,0.f,0.f},{0.f,0.f,0.f,0.f}};
  float mrowA[4] = {-INFINITY,-INFINITY,-INFINITY,-INFINITY};
  float mrowB[4] = {-INFINITY,-INFINITY,-INFINITY,-INFINITY};
  float lrowA[4] = {0.f,0.f,0.f,0.f};
  float lrowB[4] = {0.f,0.f,0.f,0.f};

  #pragma unroll 1
  for (int kt = 0; kt < 16; ++kt) {
    // ---- compute on Ks/Vs (tile kt); kv regs hold tile kt+1 in flight ----

    // QK^T for both groups: 3-term split; 4 kf reads feed 12 MFMAs
    f32x4 scA[4], scB[4];
    __builtin_amdgcn_s_setprio(1);
    #pragma unroll
    for (int ns = 0; ns < 4; ++ns) {
      bf16x8 kf0 = *(const bf16x8*)&Ks[((ns * 4 + 0) * 64 + lane) * 8];
      bf16x8 kf1 = *(const bf16x8*)&Ks[((ns * 4 + 1) * 64 + lane) * 8];
      bf16x8 kf2 = *(const bf16x8*)&Ks[((ns * 4 + 2) * 64 + lane) * 8];
      bf16x8 kf3 = *(const bf16x8*)&Ks[((ns * 4 + 3) * 64 + lane) * 8];
      f32x4 cA = {0.f,0.f,0.f,0.f}, cB = {0.f,0.f,0.f,0.f};
      cA = __builtin_amdgcn_mfma_f32_16x16x32_bf16(qfA[0], kf0, cA, 0, 0, 0);
      cB = __builtin_amdgcn_mfma_f32_16x16x32_bf16(qfB[0], kf0, cB, 0, 0, 0);
      cA = __builtin_amdgcn_mfma_f32_16x16x32_bf16(qfA[1], kf1, cA, 0, 0, 0);
      cB = __builtin_amdgcn_mfma_f32_16x16x32_bf16(qfB[1], kf1, cB, 0, 0, 0);
      cA = __builtin_amdgcn_mfma_f32_16x16x32_bf16(qfA[2], kf0, cA, 0, 0, 0);
      cB = __builtin_amdgcn_mfma_f32_16x16x32_bf16(qfB[2], kf0, cB, 0, 0, 0);
      cA = __builtin_amdgcn_mfma_f32_16x16x32_bf16(qfA[3], kf1, cA, 0, 0, 0);
      cB = __builtin_amdgcn_mfma_f32_16x16x32_bf16(qfB[3], kf1, cB, 0, 0, 0);
      cA = __builtin_amdgcn_mfma_f32_16x16x32_bf16(qfA[0], kf2, cA, 0, 0, 0);
      cB = __builtin_amdgcn_mfma_f32_16x16x32_bf16(qfB[0], kf2, cB, 0, 0, 0);
      cA = __builtin_amdgcn_mfma_f32_16x16x32_bf16(qfA[1], kf3, cA, 0, 0, 0);
      cB = __builtin_amdgcn_mfma_f32_16x16x32_bf16(qfB[1], kf3, cB, 0, 0, 0);
      scA[ns] = cA; scB[ns] = cB;
    }
    __builtin_amdgcn_s_setprio(0);

    // mask + scale (exp2 domain), row max
    float rmaxA[4] = {-INFINITY,-INFINITY,-INFINITY,-INFINITY};
    float rmaxB[4] = {-INFINITY,-INFINITY,-INFINITY,-INFINITY};
    #pragma unroll
    for (int ns = 0; ns < 4; ++ns) {
      unsigned short mk = msks[kt * 64 + ns * 16 + l16];
      #pragma unroll
      for (int r = 0; r < 4; ++r) {
        float sA2 = mk ? MSKV : scA[ns][r] * SCL;
        float sB2 = mk ? MSKV : scB[ns][r] * SCL;
        scA[ns][r] = sA2; scB[ns][r] = sB2;
        rmaxA[r] = fmaxf(rmaxA[r], sA2);
        rmaxB[r] = fmaxf(rmaxB[r], sB2);
      }
    }
    // DPP 16-lane reduce (VALU pipe, no DS traffic)
    #pragma unroll
    for (int r = 0; r < 4; ++r) {
      rmaxA[r] = rowmax16(rmaxA[r]);
      rmaxB[r] = rowmax16(rmaxB[r]);
    }

    // T13 defer-max: skip rescale when max grew by <= 8 (P bounded by 2^8)
    bool nosk = !(rmaxA[0] <= mrowA[0] + 8.f && rmaxA[1] <= mrowA[1] + 8.f &&
                  rmaxA[2] <= mrowA[2] + 8.f && rmaxA[3] <= mrowA[3] + 8.f &&
                  rmaxB[0] <= mrowB[0] + 8.f && rmaxB[1] <= mrowB[1] + 8.f &&
                  rmaxB[2] <= mrowB[2] + 8.f && rmaxB[3] <= mrowB[3] + 8.f);
    if (__any((int)nosk)) {
      #pragma unroll
      for (int r = 0; r < 4; ++r) {
        float mnA = fmaxf(mrowA[r], rmaxA[r]);
        float mnB = fmaxf(mrowB[r], rmaxB[r]);
        float aA = exp2g(mrowA[r] - mnA);
        float aB = exp2g(mrowB[r] - mnB);
        mrowA[r] = mnA; mrowB[r] = mnB;
        lrowA[r] *= aA;  lrowB[r] *= aB;
        #pragma unroll
        for (int d = 0; d < 4; ++d) { OA[d][r] *= aA; OB[d][r] *= aB; }
      }
    }

    // exp2 + write P (bf16, native cvt) to per-wave LDS in A-fragment order (A@0, B@1024)
    #pragma unroll
    for (int ns = 0; ns < 4; ++ns) {
      int key = ns * 16 + l16;
      int cbase = (((key >> 5) * 4 + ((key >> 3) & 3)) * 16 + quad * 4) * 8 + (key & 7);
      #pragma unroll
      for (int r = 0; r < 4; ++r) {
        float pA = exp2g(scA[ns][r] - mrowA[r]);
        float pB = exp2g(scB[ns][r] - mrowB[r]);
        Pw[wave][cbase + r * 8]        = __builtin_bit_cast(unsigned short, (__bf16)pA);
        Pw[wave][1024 + cbase + r * 8] = __builtin_bit_cast(unsigned short, (__bf16)pB);
      }
    }

    // P·V (wave-local): vf read once, feeds both groups; ones-MFMA gives row sums
    bf16x8 pfA[2], pfB[2];
    #pragma unroll
    for (int kk = 0; kk < 2; ++kk) {
      pfA[kk] = *(const bf16x8*)&Pw[wave][((kk * 4 + quad) * 16 + l16) * 8];
      pfB[kk] = *(const bf16x8*)&Pw[wave][1024 + ((kk * 4 + quad) * 16 + l16) * 8];
    }
    f32x4 smA = {0.f,0.f,0.f,0.f}, smB = {0.f,0.f,0.f,0.f};
    __builtin_amdgcn_s_setprio(1);
    #pragma unroll
    for (int d = 0; d < 4; ++d)
      #pragma unroll
      for (int kk = 0; kk < 2; ++kk) {
        bf16x8 vf = *(const bf16x8*)&Vs[((d * 2 + kk) * 64 + lane) * 8];
        OA[d] = __builtin_amdgcn_mfma_f32_16x16x32_bf16(pfA[kk], vf, OA[d], 0, 0, 0);
        OB[d] = __builtin_amdgcn_mfma_f32_16x16x32_bf16(pfB[kk], vf, OB[d], 0, 0, 0);
      }
    smA = __builtin_amdgcn_mfma_f32_16x16x32_bf16(pfA[0], onesv, smA, 0, 0, 0);
    smA = __builtin_amdgcn_mfma_f32_16x16x32_bf16(pfA[1], onesv, smA, 0, 0, 0);
    smB = __builtin_amdgcn_mfma_f32_16x16x32_bf16(pfB[0], onesv, smB, 0, 0, 0);
    smB = __builtin_amdgcn_mfma_f32_16x16x32_bf16(pfB[1], onesv, smB, 0, 0, 0);
    __builtin_amdgcn_s_setprio(0);
    #pragma unroll
    for (int r = 0; r < 4; ++r) { lrowA[r] += smA[r]; lrowB[r] += smB[r]; }

    // ---- tile boundary: readers of kt done -> overwrite LDS with kt+1, issue kt+2 ----
    BARRIER();
    if (kt < 15) {
      KV_WRITE();               // waits kv's vmem loads (counted, long since landed)
      KV_ISSUE(kt + 2);         // clamped inside; unconditional issue
      BARRIER();                // kt+1 visible to all waves
    }
  }

  // epilogue
  const int h = bh & 15;
  #pragma unroll
  for (int r = 0; r < 4; ++r) {
    float invA = 1.f / lrowA[r];
    float invB = 1.f / lrowB[r];
    int qA = q0 + wave * 32 + quad * 4 + r;
    float* dstA = out + ((size_t)bb * Sdim + qA) * Hdim + h * HDd;
    float* dstB = dstA + 16 * Hdim;
    #pragma unroll
    for (int d = 0; d < 4; ++d) {
      dstA[d * 16 + l16] = OA[d][r] * invA;
      dstB[d * 16 + l16] = OB[d][r] * invB;
    }
  }

#undef BARRIER
#undef KV_ISSUE
#undef KV_WRITE
}

extern "C" void kernel_launch(void* const* d_in, const int* in_sizes, int n_in,
                              void* d_out, int out_size, void* d_ws, size_t ws_size,
                              hipStream_t stream) {
  const float* hs   = (const float*)d_in[0];
  const int*   mask = (const int*)d_in[1];
  const float* w    = (const float*)d_in[2];
  const float* bias = (const float*)d_in[3];
  float* out = (float*)d_out;
  unsigned short* ws = (unsigned short*)d_ws;
  unsigned short* ao = (unsigned short*)d_out;   // A hi/lo scratch, overwritten by attn

  convert_AW<<<4096 + (N3H / 64) * (1024 / 64), 256, 0, stream>>>(hs, w, ao, ws);

  qkv_mfma<<<dim3(N3H / 128, 8192 / 128), 256, 0, stream>>>(ao, ws, bias, ws);

  attn_mfma<<<Bdim * NHd * (Sdim / 128), 256, 0, stream>>>(
      ws + Q_OFF, ws + K_OFF, ws + V_OFF, mask, out);
}

// Round 12
// 334.562 us; speedup vs baseline: 1.1012x; 1.1012x over previous
//
#include <hip/hip_runtime.h>
#include <math.h>

#define Bdim 8
#define Sdim 1024
#define Hdim 1024
#define NHd 16
#define HDd 64
#define N3H 3072

// ws layout (ushort elements)
// Q: [bh][s][128] row-major (hi|lo). K: [bh][16 tiles][8192] fragment-ordered.
// V: [bh][16 tiles][4096] fragment-ordered. W^T hi/lo planes after.
#define Q_OFF   0u
#define K_OFF   16777216u
#define V_OFF   33554432u
#define WH_OFF  41943040u
#define WL_OFF  45088768u
// d_out scratch layout (ushort elements): Ahi, Alo
#define AHI_OFF 0u
#define ALO_OFF 8388608u

typedef __bf16 bf16x8 __attribute__((ext_vector_type(8)));
typedef float  f32x4  __attribute__((ext_vector_type(4)));

__device__ __forceinline__ unsigned short f2bf(float x) {
  unsigned b = __builtin_bit_cast(unsigned, x);
  return (unsigned short)((b + 0x7FFFu + ((b >> 16) & 1u)) >> 16);
}
__device__ __forceinline__ float bf2f(unsigned short h) {
  unsigned b = ((unsigned)h) << 16;
  return __builtin_bit_cast(float, b);
}
__device__ __forceinline__ void split_hl(float v, unsigned short& h, unsigned short& l) {
  h = f2bf(v);
  l = f2bf(v - bf2f(h));
}
__device__ __forceinline__ void async16(void* lds, const void* g) {
  __builtin_amdgcn_global_load_lds((const __attribute__((address_space(1))) unsigned int*)g,
                                   (__attribute__((address_space(3))) unsigned int*)lds, 16, 0, 0);
}

// DPP-based 16-lane max reduce: masks {1,2,7,15} span (Z/2)^4 and are all DPP row-ops
// (quad_perm 0xB1 = xor1, quad_perm 0x4E = xor2, row_half_mirror 0x141 = xor7,
//  row_mirror 0x140 = xor15). VALU-pipe only — no ds_swizzle traffic.
template <int CTRL>
__device__ __forceinline__ float dppmax(float v) {
  int x = __builtin_amdgcn_mov_dpp(__builtin_bit_cast(int, v), CTRL, 0xf, 0xf, true);
  return fmaxf(v, __builtin_bit_cast(float, x));
}
__device__ __forceinline__ float rowmax16(float v) {
  v = dppmax<0xB1>(v);
  v = dppmax<0x4E>(v);
  v = dppmax<0x141>(v);
  v = dppmax<0x140>(v);
  return v;
}

// native base-2 exponential (v_exp_f32)
__device__ __forceinline__ float exp2g(float x) { return __builtin_amdgcn_exp2f(x); }

// ---------- fused convert: A -> hi/lo planes (d_out scratch); W -> W^T hi/lo (ws) ----------
__global__ __launch_bounds__(256) void convert_AW(
    const float* __restrict__ A, const float* __restrict__ W,
    unsigned short* __restrict__ aout, unsigned short* __restrict__ ws)
{
  __shared__ float T[64][65];
  const int tid = threadIdx.x;
  int bid = blockIdx.x;
  if (bid < 4096) {
    size_t i = ((size_t)bid * 256 + tid) * 8;
    float4 a0 = *(const float4*)&A[i];
    float4 a1 = *(const float4*)&A[i + 4];
    float av[8] = {a0.x, a0.y, a0.z, a0.w, a1.x, a1.y, a1.z, a1.w};
    unsigned short h[8], l[8];
    #pragma unroll
    for (int j = 0; j < 8; ++j) split_hl(av[j], h[j], l[j]);
    *(uint4*)&aout[AHI_OFF + i] = *(uint4*)h;
    *(uint4*)&aout[ALO_OFF + i] = *(uint4*)l;
    return;
  }
  bid -= 4096;
  const int n0 = (bid % (N3H / 64)) * 64;
  const int k0 = (bid / (N3H / 64)) * 64;
  #pragma unroll
  for (int r = 0; r < 4; ++r) {
    int k = r * 16 + (tid >> 4);
    int n = (tid & 15) * 4;
    float4 v = *(const float4*)&W[(size_t)(k0 + k) * N3H + n0 + n];
    T[k][n + 0] = v.x; T[k][n + 1] = v.y; T[k][n + 2] = v.z; T[k][n + 3] = v.w;
  }
  __syncthreads();
  int n = tid >> 2;
  int kl = (tid & 3) * 16;
  unsigned short h[16], l[16];
  #pragma unroll
  for (int i = 0; i < 16; ++i) split_hl(T[kl + i][n], h[i], l[i]);
  size_t base = (size_t)(n0 + n) * 1024 + k0 + kl;
  *(uint4*)&ws[WH_OFF + base]     = *(uint4*)&h[0];
  *(uint4*)&ws[WH_OFF + base + 8] = *(uint4*)&h[8];
  *(uint4*)&ws[WL_OFF + base]     = *(uint4*)&l[0];
  *(uint4*)&ws[WL_OFF + base + 8] = *(uint4*)&l[8];
}

// ---------- MFMA QKV GEMM: C = A(8192x1024) * W(1024x3072) + bias ----------
// (R0 version: 128x128 tile, 16x16x32, 2 blocks/CU — proven 152-155 us. FROZEN.)
__global__ __launch_bounds__(256, 2) void qkv_mfma(
    const unsigned short* __restrict__ ao,
    const unsigned short* __restrict__ ws,
    const float* __restrict__ bias,
    unsigned short* __restrict__ wso)
{
  __shared__ unsigned short sA[2][128 * 32];
  __shared__ unsigned short sB[2][128 * 32];

  const int tid  = threadIdx.x;
  const int wave = tid >> 6;
  const int lane = tid & 63;
  const int l16  = lane & 15;
  const int quad = lane >> 4;

  const int n0 = blockIdx.x * 128;
  const int m0 = blockIdx.y * 128;
  const int wm = (wave >> 1) * 64;
  const int wn = (wave & 1) * 64;

  const unsigned short* Ah = ao + AHI_OFF;
  const unsigned short* Al = ao + ALO_OFF;
  const unsigned short* Wh = ws + WH_OFF;
  const unsigned short* Wl = ws + WL_OFF;

  f32x4 acc[4][4];
  #pragma unroll
  for (int i = 0; i < 4; ++i)
    #pragma unroll
    for (int j = 0; j < 4; ++j) acc[i][j] = (f32x4){0.f, 0.f, 0.f, 0.f};

  for (int kt = 0; kt < 1024; kt += 32) {
    __syncthreads();
    #pragma unroll
    for (int r = 0; r < 2; ++r) {
      int chunk = r * 256 + tid;
      int row = chunk >> 2;
      int c8  = (chunk & 3) << 3;
      int ldsoff = (r * 256 + wave * 64) * 8;
      async16(&sA[0][ldsoff], &Ah[(size_t)(m0 + row) * 1024 + kt + c8]);
      async16(&sA[1][ldsoff], &Al[(size_t)(m0 + row) * 1024 + kt + c8]);
      async16(&sB[0][ldsoff], &Wh[(size_t)(n0 + row) * 1024 + kt + c8]);
      async16(&sB[1][ldsoff], &Wl[(size_t)(n0 + row) * 1024 + kt + c8]);
    }
    __syncthreads();

    bf16x8 af[4][2], bf[4][2];
    #pragma unroll
    for (int i = 0; i < 4; ++i) {
      int row = wm + i * 16 + l16;
      af[i][0] = *(const bf16x8*)&sA[0][row * 32 + quad * 8];
      af[i][1] = *(const bf16x8*)&sA[1][row * 32 + quad * 8];
    }
    #pragma unroll
    for (int j = 0; j < 4; ++j) {
      int row = wn + j * 16 + l16;
      bf[j][0] = *(const bf16x8*)&sB[0][row * 32 + quad * 8];
      bf[j][1] = *(const bf16x8*)&sB[1][row * 32 + quad * 8];
    }
    #pragma unroll
    for (int i = 0; i < 4; ++i)
      #pragma unroll
      for (int j = 0; j < 4; ++j) {
        acc[i][j] = __builtin_amdgcn_mfma_f32_16x16x32_bf16(af[i][0], bf[j][0], acc[i][j], 0, 0, 0);
        acc[i][j] = __builtin_amdgcn_mfma_f32_16x16x32_bf16(af[i][1], bf[j][0], acc[i][j], 0, 0, 0);
        acc[i][j] = __builtin_amdgcn_mfma_f32_16x16x32_bf16(af[i][0], bf[j][1], acc[i][j], 0, 0, 0);
      }
  }

  const int ncol0 = n0 + wn;
  const int which = (ncol0 >> 6) % 3;
  const int head  = ncol0 / 192;
  const int mrow0 = m0 + wm;
  const int bb = mrow0 >> 10;
  const int sb = mrow0 & 1023;
  const int bh = bb * NHd + head;

  float bs[4];
  #pragma unroll
  for (int j = 0; j < 4; ++j) bs[j] = bias[ncol0 + j * 16 + l16];

  if (which == 0) {
    unsigned short* dst = wso + Q_OFF + ((size_t)bh * Sdim + sb) * 128;
    #pragma unroll
    for (int i = 0; i < 4; ++i)
      #pragma unroll
      for (int j = 0; j < 4; ++j) {
        int d = j * 16 + l16;
        #pragma unroll
        for (int r = 0; r < 4; ++r) {
          int s = i * 16 + quad * 4 + r;
          unsigned short h, l;
          split_hl(acc[i][j][r] + bs[j], h, l);
          dst[(size_t)s * 128 + d]      = h;
          dst[(size_t)s * 128 + 64 + d] = l;
        }
      }
  } else if (which == 1) {
    unsigned short* dst = wso + K_OFF + (size_t)bh * 131072 + (size_t)(sb >> 6) * 8192;
    #pragma unroll
    for (int i = 0; i < 4; ++i)
      #pragma unroll
      for (int j = 0; j < 4; ++j) {
        int c = j * 16 + l16;
        #pragma unroll
        for (int r = 0; r < 4; ++r) {
          int sp = i * 16 + quad * 4 + r;
          int idx = ((((sp >> 4) * 4 + (c >> 5)) * 64 + ((c >> 3) & 3) * 16 + (sp & 15)) << 3) + (c & 7);
          unsigned short h, l;
          split_hl(acc[i][j][r] + bs[j], h, l);
          dst[idx]        = h;
          dst[idx + 1024] = l;
        }
      }
  } else {
    unsigned short* dst = wso + V_OFF + (size_t)bh * 65536 + (size_t)(sb >> 6) * 4096;
    #pragma unroll
    for (int i = 0; i < 4; ++i)
      #pragma unroll
      for (int j = 0; j < 4; ++j) {
        int dr = j * 16 + l16;
        int ky = i * 16 + quad * 4;
        int idx = ((((dr >> 4) * 2 + (ky >> 5)) * 64 + ((ky >> 3) & 3) * 16 + (dr & 15)) << 3) + (ky & 7);
        unsigned short p[4];
        #pragma unroll
        for (int r = 0; r < 4; ++r) p[r] = f2bf(acc[i][j][r] + bs[j]);
        *(uint2*)&dst[idx] = *(uint2*)p;
      }
  }
}

// -------- MFMA flash attention: 128 q/block (32 q/wave, A/B groups), DMA staging ---------
// R10/R8 structure (single buffer, 3 blk/CU — cross-block TLP hides staging latency;
// R7 dbuf@2blk/CU and R11 reg-staged T14 both failed to beat it). Ones-MFMA row-sum,
// DPP max-reduce, exp2-domain softmax, T13 defer-max, T5 setprio. BEST: 346.7 us total.
__global__ __launch_bounds__(256, 3) void attn_mfma(
    const unsigned short* __restrict__ qhl,
    const unsigned short* __restrict__ khl,   // fragment-ordered tiles
    const unsigned short* __restrict__ vt,    // fragment-ordered tiles
    const int* __restrict__ mask,
    float* __restrict__ out)
{
  __shared__ unsigned short Ks[8192];
  __shared__ unsigned short Vs[4096];
  __shared__ unsigned short Pw[4][2048];
  __shared__ unsigned short msks[1024];

  const int tid  = threadIdx.x;
  const int wave = tid >> 6;
  const int lane = tid & 63;
  const int l16  = lane & 15;
  const int quad = lane >> 4;

  const int xcd = blockIdx.x & 7;
  const int s_  = blockIdx.x >> 3;                           // 0..127
  const int bh  = xcd + ((s_ & 7) << 3) + ((s_ >> 6) << 6);  // 0..127 (bijective)
  const int qt  = (s_ >> 3) & 7;                             // 0..7
  const int bb  = bh >> 4;
  const int q0  = qt * 128;

  const float SCL = 11.5415603f;    // 8 * log2(e): softmax in exp2 domain (exact transform)
  const float MSKV = -14427.0f;     // -10000 * log2(e), rounded down

  const unsigned short* kplane = khl + (size_t)bh * 131072;
  const unsigned short* vplane = vt  + (size_t)bh * 65536;

  // all-ones B fragment for row-sum MFMA
  bf16x8 onesv;
  #pragma unroll
  for (int i = 0; i < 8; ++i) onesv[i] = (__bf16)1.0f;

  // mask row preload (once)
  {
    int4 mv = *(const int4*)&mask[bb * Sdim + tid * 4];
    msks[tid * 4 + 0] = (unsigned short)(mv.x ? 1 : 0);
    msks[tid * 4 + 1] = (unsigned short)(mv.y ? 1 : 0);
    msks[tid * 4 + 2] = (unsigned short)(mv.z ? 1 : 0);
    msks[tid * 4 + 3] = (unsigned short)(mv.w ? 1 : 0);
  }

  // Q fragments direct from global: group A rows = q0+wave*32+l16, group B = +16
  bf16x8 qfA[4], qfB[4];
  {
    int rowA = q0 + wave * 32 + l16;
    const unsigned short* srcA = qhl + ((size_t)bh * Sdim + rowA) * 128;
    const unsigned short* srcB = srcA + 16 * 128;
    #pragma unroll
    for (int kk = 0; kk < 4; ++kk) {
      qfA[kk] = *(const bf16x8*)&srcA[kk * 32 + quad * 8];
      qfB[kk] = *(const bf16x8*)&srcB[kk * 32 + quad * 8];
    }
  }

  f32x4 OA[4] = {{0.f,0.f,0.f,0.f},{0.f,0.f,0.f,0.f},{0.f,0.f,0.f,0.f},{0.f,0.f,0.f,0.f}};
  f32x4 OB[4] = {{0.f,0.f,0.f,0.f},{0.f,0.f,0.f,0.f},{0.f,0.f,0.f,0.f},{0.f,0.f,0.f,0.f}};
  float mrowA[4] = {-INFINITY,-INFINITY,-INFINITY,-INFINITY};
  float mrowB[4] = {-INFINITY,-INFINITY,-INFINITY,-INFINITY};
  float lrowA[4] = {0.f,0.f,0.f,0.f};
  float lrowB[4] = {0.f,0.f,0.f,0.f};

  #pragma unroll 1
  for (int kt = 0; kt < 16; ++kt) {
    __syncthreads();   // previous tile's readers done (also orders msks on kt=0)
    {
      const unsigned short* ksrc = kplane + (size_t)kt * 8192;
      const unsigned short* vsrc = vplane + (size_t)kt * 4096;
      #pragma unroll
      for (int r = 0; r < 4; ++r)
        async16(&Ks[(r * 256 + tid) * 8], &ksrc[(size_t)(r * 256 + tid) * 8]);
      #pragma unroll
      for (int r = 0; r < 2; ++r)
        async16(&Vs[(r * 256 + tid) * 8], &vsrc[(size_t)(r * 256 + tid) * 8]);
    }
    __syncthreads();   // staged tile visible (drains vmcnt)

    // QK^T for both groups: 3-term split; 4 kf reads feed 12 MFMAs
    f32x4 scA[4], scB[4];
    __builtin_amdgcn_s_setprio(1);
    #pragma unroll
    for (int ns = 0; ns < 4; ++ns) {
      bf16x8 kf0 = *(const bf16x8*)&Ks[((ns * 4 + 0) * 64 + lane) * 8];
      bf16x8 kf1 = *(const bf16x8*)&Ks[((ns * 4 + 1) * 64 + lane) * 8];
      bf16x8 kf2 = *(const bf16x8*)&Ks[((ns * 4 + 2) * 64 + lane) * 8];
      bf16x8 kf3 = *(const bf16x8*)&Ks[((ns * 4 + 3) * 64 + lane) * 8];
      f32x4 cA = {0.f,0.f,0.f,0.f}, cB = {0.f,0.f,0.f,0.f};
      cA = __builtin_amdgcn_mfma_f32_16x16x32_bf16(qfA[0], kf0, cA, 0, 0, 0);
      cB = __builtin_amdgcn_mfma_f32_16x16x32_bf16(qfB[0], kf0, cB, 0, 0, 0);
      cA = __builtin_amdgcn_mfma_f32_16x16x32_bf16(qfA[1], kf1, cA, 0, 0, 0);
      cB = __builtin_amdgcn_mfma_f32_16x16x32_bf16(qfB[1], kf1, cB, 0, 0, 0);
      cA = __builtin_amdgcn_mfma_f32_16x16x32_bf16(qfA[2], kf0, cA, 0, 0, 0);
      cB = __builtin_amdgcn_mfma_f32_16x16x32_bf16(qfB[2], kf0, cB, 0, 0, 0);
      cA = __builtin_amdgcn_mfma_f32_16x16x32_bf16(qfA[3], kf1, cA, 0, 0, 0);
      cB = __builtin_amdgcn_mfma_f32_16x16x32_bf16(qfB[3], kf1, cB, 0, 0, 0);
      cA = __builtin_amdgcn_mfma_f32_16x16x32_bf16(qfA[0], kf2, cA, 0, 0, 0);
      cB = __builtin_amdgcn_mfma_f32_16x16x32_bf16(qfB[0], kf2, cB, 0, 0, 0);
      cA = __builtin_amdgcn_mfma_f32_16x16x32_bf16(qfA[1], kf3, cA, 0, 0, 0);
      cB = __builtin_amdgcn_mfma_f32_16x16x32_bf16(qfB[1], kf3, cB, 0, 0, 0);
      scA[ns] = cA; scB[ns] = cB;
    }
    __builtin_amdgcn_s_setprio(0);

    // mask + scale (exp2 domain), row max
    float rmaxA[4] = {-INFINITY,-INFINITY,-INFINITY,-INFINITY};
    float rmaxB[4] = {-INFINITY,-INFINITY,-INFINITY,-INFINITY};
    #pragma unroll
    for (int ns = 0; ns < 4; ++ns) {
      unsigned short mk = msks[kt * 64 + ns * 16 + l16];
      #pragma unroll
      for (int r = 0; r < 4; ++r) {
        float sA2 = mk ? MSKV : scA[ns][r] * SCL;
        float sB2 = mk ? MSKV : scB[ns][r] * SCL;
        scA[ns][r] = sA2; scB[ns][r] = sB2;
        rmaxA[r] = fmaxf(rmaxA[r], sA2);
        rmaxB[r] = fmaxf(rmaxB[r], sB2);
      }
    }
    // DPP 16-lane reduce (VALU pipe, no DS traffic)
    #pragma unroll
    for (int r = 0; r < 4; ++r) {
      rmaxA[r] = rowmax16(rmaxA[r]);
      rmaxB[r] = rowmax16(rmaxB[r]);
    }

    // T13 defer-max: skip rescale when max grew by <= 8 (P bounded by 2^8)
    bool nosk = !(rmaxA[0] <= mrowA[0] + 8.f && rmaxA[1] <= mrowA[1] + 8.f &&
                  rmaxA[2] <= mrowA[2] + 8.f && rmaxA[3] <= mrowA[3] + 8.f &&
                  rmaxB[0] <= mrowB[0] + 8.f && rmaxB[1] <= mrowB[1] + 8.f &&
                  rmaxB[2] <= mrowB[2] + 8.f && rmaxB[3] <= mrowB[3] + 8.f);
    if (__any((int)nosk)) {
      #pragma unroll
      for (int r = 0; r < 4; ++r) {
        float mnA = fmaxf(mrowA[r], rmaxA[r]);
        float mnB = fmaxf(mrowB[r], rmaxB[r]);
        float aA = exp2g(mrowA[r] - mnA);
        float aB = exp2g(mrowB[r] - mnB);
        mrowA[r] = mnA; mrowB[r] = mnB;
        lrowA[r] *= aA;  lrowB[r] *= aB;
        #pragma unroll
        for (int d = 0; d < 4; ++d) { OA[d][r] *= aA; OB[d][r] *= aB; }
      }
    }

    // exp2 + write P (bf16, native cvt) to per-wave LDS in A-fragment order (A@0, B@1024)
    #pragma unroll
    for (int ns = 0; ns < 4; ++ns) {
      int key = ns * 16 + l16;
      int cbase = (((key >> 5) * 4 + ((key >> 3) & 3)) * 16 + quad * 4) * 8 + (key & 7);
      #pragma unroll
      for (int r = 0; r < 4; ++r) {
        float pA = exp2g(scA[ns][r] - mrowA[r]);
        float pB = exp2g(scB[ns][r] - mrowB[r]);
        Pw[wave][cbase + r * 8]        = __builtin_bit_cast(unsigned short, (__bf16)pA);
        Pw[wave][1024 + cbase + r * 8] = __builtin_bit_cast(unsigned short, (__bf16)pB);
      }
    }

    // P·V (wave-local): vf read once, feeds both groups; ones-MFMA gives row sums
    bf16x8 pfA[2], pfB[2];
    #pragma unroll
    for (int kk = 0; kk < 2; ++kk) {
      pfA[kk] = *(const bf16x8*)&Pw[wave][((kk * 4 + quad) * 16 + l16) * 8];
      pfB[kk] = *(const bf16x8*)&Pw[wave][1024 + ((kk * 4 + quad) * 16 + l16) * 8];
    }
    f32x4 smA = {0.f,0.f,0.f,0.f}, smB = {0.f,0.f,0.f,0.f};
    __builtin_amdgcn_s_setprio(1);
    #pragma unroll
    for (int d = 0; d < 4; ++d)
      #pragma unroll
      for (int kk = 0; kk < 2; ++kk) {
        bf16x8 vf = *(const bf16x8*)&Vs[((d * 2 + kk) * 64 + lane) * 8];
        OA[d] = __builtin_amdgcn_mfma_f32_16x16x32_bf16(pfA[kk], vf, OA[d], 0, 0, 0);
        OB[d] = __builtin_amdgcn_mfma_f32_16x16x32_bf16(pfB[kk], vf, OB[d], 0, 0, 0);
      }
    smA = __builtin_amdgcn_mfma_f32_16x16x32_bf16(pfA[0], onesv, smA, 0, 0, 0);
    smA = __builtin_amdgcn_mfma_f32_16x16x32_bf16(pfA[1], onesv, smA, 0, 0, 0);
    smB = __builtin_amdgcn_mfma_f32_16x16x32_bf16(pfB[0], onesv, smB, 0, 0, 0);
    smB = __builtin_amdgcn_mfma_f32_16x16x32_bf16(pfB[1], onesv, smB, 0, 0, 0);
    __builtin_amdgcn_s_setprio(0);
    #pragma unroll
    for (int r = 0; r < 4; ++r) { lrowA[r] += smA[r]; lrowB[r] += smB[r]; }
  }

  // epilogue
  const int h = bh & 15;
  #pragma unroll
  for (int r = 0; r < 4; ++r) {
    float invA = 1.f / lrowA[r];
    float invB = 1.f / lrowB[r];
    int qA = q0 + wave * 32 + quad * 4 + r;
    float* dstA = out + ((size_t)bb * Sdim + qA) * Hdim + h * HDd;
    float* dstB = dstA + 16 * Hdim;
    #pragma unroll
    for (int d = 0; d < 4; ++d) {
      dstA[d * 16 + l16] = OA[d][r] * invA;
      dstB[d * 16 + l16] = OB[d][r] * invB;
    }
  }
}

extern "C" void kernel_launch(void* const* d_in, const int* in_sizes, int n_in,
                              void* d_out, int out_size, void* d_ws, size_t ws_size,
                              hipStream_t stream) {
  const float* hs   = (const float*)d_in[0];
  const int*   mask = (const int*)d_in[1];
  const float* w    = (const float*)d_in[2];
  const float* bias = (const float*)d_in[3];
  float* out = (float*)d_out;
  unsigned short* ws = (unsigned short*)d_ws;
  unsigned short* ao = (unsigned short*)d_out;   // A hi/lo scratch, overwritten by attn

  convert_AW<<<4096 + (N3H / 64) * (1024 / 64), 256, 0, stream>>>(hs, w, ao, ws);

  qkv_mfma<<<dim3(N3H / 128, 8192 / 128), 256, 0, stream>>>(ao, ws, bias, ws);

  attn_mfma<<<Bdim * NHd * (Sdim / 128), 256, 0, stream>>>(
      ws + Q_OFF, ws + K_OFF, ws + V_OFF, mask, out);
}